// Round 2
// baseline (256.973 us; speedup 1.0000x reference)
//
#include <hip/hip_runtime.h>
#include <hip/hip_bf16.h>

// ---------------------------------------------------------------------------
// Causal single-head attention (B=4, T=4096, C=1024, H=64), fp32-accurate via
// split-bf16 (hi/lo) MFMA emulation. scale = HEAD_COUNT^-0.5 = 0.25.
//
//   Kernel 1 qkv_proj: x@Wq/Wk/Wv -> q,k (hi+lo bf16, [b*T+t][64]) and
//                      V^T (hi+lo bf16, [b*64+h][4096]) in d_ws.
//   Kernel 2 attn:     swapped-operand flash attention (S^T = K*Q^T via
//                      mfma_32x32x16_bf16), softmax per-lane (q is lane-local),
//                      P^T fragments built IN REGISTERS (no LDS round trip),
//                      8 mod-8 key-stripe waves per 64-row Q tile, wave-private
//                      LDS staging, single end-of-kernel 8-way LDS merge.
// ---------------------------------------------------------------------------

typedef __attribute__((ext_vector_type(8))) short short8_t;   // 8 bf16
typedef __attribute__((ext_vector_type(4))) float f32x4;
typedef __attribute__((ext_vector_type(16))) float f32x16;

#define MFMA16(a, b, c) __builtin_amdgcn_mfma_f32_16x16x32_bf16((a), (b), (c), 0, 0, 0)
#define MFMA32(a, b, c) __builtin_amdgcn_mfma_f32_32x32x16_bf16((a), (b), (c), 0, 0, 0)

__device__ __forceinline__ unsigned short f2bf(float f) {
  union { float f; unsigned int u; } v; v.f = f;
  unsigned int u = v.u;
  u += 0x7FFFu + ((u >> 16) & 1u);   // RNE
  return (unsigned short)(u >> 16);
}
__device__ __forceinline__ float bf2f(unsigned short h) {
  union { unsigned int u; float f; } v; v.u = ((unsigned int)h) << 16;
  return v.f;
}

// ---------------------------------------------------------------------------
// Kernel 1: QKV projection. x[16384,1024] fp32 @ W[1024,64] x3, split-bf16
// (hh+hl+lh). Block: 256 thr / 4 waves; tile 64 rows x 192 cols; K-step 32.
// ---------------------------------------------------------------------------
__global__ __launch_bounds__(256) void qkv_proj(
    const float* __restrict__ x,  const float* __restrict__ Wq,
    const float* __restrict__ Wk, const float* __restrict__ Wv,
    unsigned short* __restrict__ qh, unsigned short* __restrict__ ql,
    unsigned short* __restrict__ kh, unsigned short* __restrict__ kl,
    unsigned short* __restrict__ vth, unsigned short* __restrict__ vtl)
{
  __shared__ alignas(16) unsigned short Ah[64][40];   // +8 pad
  __shared__ alignas(16) unsigned short Al[64][40];
  __shared__ alignas(16) unsigned short Bh[192][40];  // W^T tiles
  __shared__ alignas(16) unsigned short Bl[192][40];

  const int tid  = threadIdx.x;
  const int wave = tid >> 6;
  const int lane = tid & 63;
  const int g    = lane >> 4;
  const int c    = lane & 15;
  const int m0   = blockIdx.x * 64;

  f32x4 acc[4][3];
#pragma unroll
  for (int m = 0; m < 4; ++m)
#pragma unroll
    for (int nn = 0; nn < 3; ++nn) acc[m][nn] = (f32x4){0.f, 0.f, 0.f, 0.f};

  for (int k0 = 0; k0 < 1024; k0 += 32) {
    __syncthreads();
    // stage x tile (64x32 fp32 -> hi/lo bf16)
#pragma unroll
    for (int it = 0; it < 2; ++it) {
      int chunk = tid + it * 256;
      int row = chunk >> 3, ch = chunk & 7;
      const float4 vx = *reinterpret_cast<const float4*>(
          x + (size_t)(m0 + row) * 1024 + k0 + ch * 4);
#pragma unroll
      for (int j = 0; j < 4; ++j) {
        float f = ((const float*)&vx)[j];
        unsigned short h = f2bf(f);
        Ah[row][ch * 4 + j] = h;
        Al[row][ch * 4 + j] = f2bf(f - bf2f(h));
      }
    }
    // stage W tiles transposed (3 x 32x64 fp32 -> hi/lo); mat constant per it
    const float* const Ws[3] = {Wq, Wk, Wv};
#pragma unroll
    for (int it = 0; it < 6; ++it) {
      int chunk = tid + it * 256;
      int mat = chunk >> 9;            // == it>>1, compile-time per iteration
      int cid = chunk & 511;
      int kk = cid >> 4, ch = cid & 15;
      const float4 vw = *reinterpret_cast<const float4*>(
          Ws[mat] + (size_t)(k0 + kk) * 64 + ch * 4);
#pragma unroll
      for (int j = 0; j < 4; ++j) {
        float f = ((const float*)&vw)[j];
        unsigned short h = f2bf(f);
        int n = mat * 64 + ch * 4 + j;
        Bh[n][kk] = h;
        Bl[n][kk] = f2bf(f - bf2f(h));
      }
    }
    __syncthreads();

    short8_t a_h[4], a_l[4];
#pragma unroll
    for (int m = 0; m < 4; ++m) {
      a_h[m] = *reinterpret_cast<const short8_t*>(&Ah[m * 16 + c][g * 8]);
      a_l[m] = *reinterpret_cast<const short8_t*>(&Al[m * 16 + c][g * 8]);
    }
#pragma unroll
    for (int nn = 0; nn < 3; ++nn) {
      const int nt = wave * 3 + nn;
      short8_t b_h = *reinterpret_cast<const short8_t*>(&Bh[nt * 16 + c][g * 8]);
      short8_t b_l = *reinterpret_cast<const short8_t*>(&Bl[nt * 16 + c][g * 8]);
#pragma unroll
      for (int m = 0; m < 4; ++m) {
        acc[m][nn] = MFMA16(a_h[m], b_h, acc[m][nn]);
        acc[m][nn] = MFMA16(a_h[m], b_l, acc[m][nn]);
        acc[m][nn] = MFMA16(a_l[m], b_h, acc[m][nn]);
      }
    }
  }

  // epilogue: C/D layout col=lane&15, row=g*4+r (m89-verified)
#pragma unroll
  for (int m = 0; m < 4; ++m) {
#pragma unroll
    for (int nn = 0; nn < 3; ++nn) {
      const int nt  = wave * 3 + nn;
      const int mat = nt >> 2;
      const int col = (nt & 3) * 16 + c;
#pragma unroll
      for (int r = 0; r < 4; ++r) {
        float f = acc[m][nn][r];
        int row = m0 + m * 16 + g * 4 + r;         // global token row
        unsigned short h = f2bf(f);
        unsigned short lo = f2bf(f - bf2f(h));
        if (mat == 0) {
          size_t idx = (size_t)row * 64 + col;
          qh[idx] = h; ql[idx] = lo;
        } else if (mat == 1) {
          size_t idx = (size_t)row * 64 + col;
          kh[idx] = h; kl[idx] = lo;
        } else {
          // V^T: [b*64 + h-col][t]
          int bb = row >> 12, trow = row & 4095;
          size_t idx = ((size_t)(bb * 64 + col)) * 4096 + trow;
          vth[idx] = h; vtl[idx] = lo;
        }
      }
    }
  }
}

// ---------------------------------------------------------------------------
// Kernel 2: swapped-operand flash attention.
// Grid 256 = (b, jt). Block 512 thr = 8 waves; wave ws = key stripe
// (kti ≡ ws mod 8, 32-key tiles). Per wave: full 64-q width, Q hi/lo in regs,
// K (XOR-swizzled) + V^T (pitch-40) staged in wave-private LDS.
// D-layout (m74/m101): col = lane&31, row = (r&3)+8*(r>>2)+4*(lane>>5).
// ---------------------------------------------------------------------------
#define MASKVAL (-3.0e38f)
#define MINIT   (-1.0e30f)

__global__ __launch_bounds__(512, 2) void attn(
    const unsigned short* __restrict__ qh, const unsigned short* __restrict__ ql,
    const unsigned short* __restrict__ kh, const unsigned short* __restrict__ kl,
    const unsigned short* __restrict__ vth, const unsigned short* __restrict__ vtl,
    float* __restrict__ out)
{
  // per-wave: Kh 4096B, Kl 4096B, Vh 5120B, Vl 5120B = 18432B; x8 = 144 KiB
  __shared__ alignas(16) unsigned char smem[147456];

  const int tid = threadIdx.x;
  const int ws  = tid >> 6;        // stripe / wave id
  const int l   = tid & 63;
  const int h5  = l >> 5;
  const int l31 = l & 31;
  const int bid = blockIdx.x;
  const int bb  = bid >> 6;
  const int jt  = bid & 63;
  const int t0  = jt * 64;

  unsigned short* Kh = (unsigned short*)(smem + ws * 18432);
  unsigned short* Kl = (unsigned short*)(smem + ws * 18432 + 4096);
  unsigned short* Vh = (unsigned short*)(smem + ws * 18432 + 8192);   // [64][40]
  unsigned short* Vl = (unsigned short*)(smem + ws * 18432 + 13312);

  const float CE = 0.36067376022224085f;  // 0.25 * log2(e)

  // ---- Q^T B-fragments, held in registers (row = t0 + qt*32 + l31) ----
  short8_t qf_h[2][4], qf_l[2][4];
#pragma unroll
  for (int qt = 0; qt < 2; ++qt)
#pragma unroll
    for (int c = 0; c < 4; ++c) {
      size_t off = ((size_t)(bb * 4096 + t0 + qt * 32 + l31)) * 64 + c * 16 + h5 * 8;
      qf_h[qt][c] = *reinterpret_cast<const short8_t*>(qh + off);
      qf_l[qt][c] = *reinterpret_cast<const short8_t*>(ql + off);
    }

  f32x16 ot[2][2];                         // [ht][qt] = O^T tiles
#pragma unroll
  for (int a = 0; a < 2; ++a)
#pragma unroll
    for (int b2 = 0; b2 < 2; ++b2)
#pragma unroll
      for (int r = 0; r < 16; ++r) ot[a][b2][r] = 0.f;
  float mreg[2] = {MINIT, MINIT};
  float lreg[2] = {0.f, 0.f};

  const int ktimax = (t0 + 63) >> 5;       // last 32-key tile index

  for (int kti = ws; kti <= ktimax; kti += 8) {
    const int s0 = kti * 32;

    // ---- stage K [32][64] (XOR swizzle (key&7)<<4 on byte) ----
#pragma unroll
    for (int i = 0; i < 4; ++i) {
      int k2 = i * 8 + (l >> 3);
      int hh = (l & 7) * 8;
      size_t gidx = ((size_t)(bb * 4096 + s0 + k2)) * 64 + hh;
      short8_t a = *reinterpret_cast<const short8_t*>(kh + gidx);
      short8_t b2 = *reinterpret_cast<const short8_t*>(kl + gidx);
      int wo = k2 * 64 + (hh ^ ((k2 & 7) << 3));
      *reinterpret_cast<short8_t*>(Kh + wo) = a;
      *reinterpret_cast<short8_t*>(Kl + wo) = b2;
    }
    // ---- stage V^T [64][40] (pitch 40 ushorts = 80B: conflict-minimal) ----
#pragma unroll
    for (int i = 0; i < 4; ++i) {
      int hv = i * 16 + (l >> 2);
      int kv = (l & 3) * 8;
      size_t gidx = ((size_t)(bb * 64 + hv)) * 4096 + s0 + kv;
      short8_t a = *reinterpret_cast<const short8_t*>(vth + gidx);
      short8_t b2 = *reinterpret_cast<const short8_t*>(vtl + gidx);
      int wo = hv * 40 + kv;
      *reinterpret_cast<short8_t*>(Vh + wo) = a;
      *reinterpret_cast<short8_t*>(Vl + wo) = b2;
    }
    // (same-wave ds_write -> ds_read: LDS pipe is in-order per wave;
    //  compiler inserts the lgkmcnt waits)

    // ---- K A-fragments (shared across qt) ----
    short8_t kf_h[4], kf_l[4];
#pragma unroll
    for (int c = 0; c < 4; ++c) {
      int ko = l31 * 64 + ((c * 16 + h5 * 8) ^ ((l31 & 7) << 3));
      kf_h[c] = *reinterpret_cast<const short8_t*>(Kh + ko);
      kf_l[c] = *reinterpret_cast<const short8_t*>(Kl + ko);
    }

    int pb0[2][4], pb1[2][4], plb0[2][4], plb1[2][4];  // [kc][dword], qt split

    // ---- per qt: S^T = K*Q^T, softmax, P^T frag build ----
#pragma unroll
    for (int qt = 0; qt < 2; ++qt) {
      int (*pb)[4]  = (qt == 0) ? pb0 : pb1;
      int (*plb)[4] = (qt == 0) ? plb0 : plb1;
      if (s0 > t0 + qt * 32 + 31) {   // tile fully masked for this qt
#pragma unroll
        for (int kc = 0; kc < 2; ++kc)
#pragma unroll
          for (int d = 0; d < 4; ++d) { pb[kc][d] = 0; plb[kc][d] = 0; }
        continue;
      }

      f32x16 st;
#pragma unroll
      for (int r = 0; r < 16; ++r) st[r] = 0.f;
#pragma unroll
      for (int c = 0; c < 4; ++c) {
        st = MFMA32(kf_h[c], qf_h[qt][c], st);
        st = MFMA32(kf_h[c], qf_l[qt][c], st);
        st = MFMA32(kf_l[c], qf_h[qt][c], st);
      }

      // causal mask (only near-diagonal tiles)
      if (s0 + 31 > t0 + qt * 32) {
        int qg = t0 + qt * 32 + l31;
#pragma unroll
        for (int r = 0; r < 16; ++r) {
          int keyg = s0 + (r & 3) + 8 * (r >> 2) + 4 * h5;
          if (keyg > qg) st[r] = MASKVAL;
        }
      }

      // online softmax; q is lane-local: in-lane reduce + one half-exchange
      float pm = st[0];
#pragma unroll
      for (int r = 1; r < 16; ++r) pm = fmaxf(pm, st[r]);
      pm = fmaxf(pm, __shfl_xor(pm, 32));
      float mnew = fmaxf(mreg[qt], pm);
      float fs = __builtin_amdgcn_exp2f((mreg[qt] - mnew) * CE);
      mreg[qt] = mnew;
      lreg[qt] *= fs;
#pragma unroll
      for (int ht = 0; ht < 2; ++ht) ot[ht][qt] *= fs;

      float p[16]; float rs = 0.f;
#pragma unroll
      for (int r = 0; r < 16; ++r) {
        p[r] = __builtin_amdgcn_exp2f((st[r] - mnew) * CE);
        rs += p[r];
      }
      rs += __shfl_xor(rs, 32);
      lreg[qt] += rs;

      // pack P (hi) and P-lo into key-pair dwords; exchange halves via shfl
      int w[8], wl[8], pw[8], pwl[8];
#pragma unroll
      for (int i = 0; i < 8; ++i) {
        unsigned short b0 = f2bf(p[2 * i]), b1 = f2bf(p[2 * i + 1]);
        w[i] = (int)((unsigned)b0 | ((unsigned)b1 << 16));
        float l0 = p[2 * i] - bf2f(b0), l1 = p[2 * i + 1] - bf2f(b1);
        wl[i] = (int)((unsigned)f2bf(l0) | ((unsigned)f2bf(l1) << 16));
      }
#pragma unroll
      for (int i = 0; i < 8; ++i) {
        pw[i]  = __shfl_xor(w[i], 32);
        pwl[i] = __shfl_xor(wl[i], 32);
      }
      // B-frag dwords for keys kc*16 + h5*8 + {0..7} (derived from D-layout)
#pragma unroll
      for (int kc = 0; kc < 2; ++kc) {
        pb[kc][0]  = h5 ? pw[4 * kc + 2]  : w[4 * kc];
        pb[kc][1]  = h5 ? pw[4 * kc + 3]  : w[4 * kc + 1];
        pb[kc][2]  = h5 ? w[4 * kc + 2]   : pw[4 * kc];
        pb[kc][3]  = h5 ? w[4 * kc + 3]   : pw[4 * kc + 1];
        plb[kc][0] = h5 ? pwl[4 * kc + 2] : wl[4 * kc];
        plb[kc][1] = h5 ? pwl[4 * kc + 3] : wl[4 * kc + 1];
        plb[kc][2] = h5 ? wl[4 * kc + 2]  : pwl[4 * kc];
        plb[kc][3] = h5 ? wl[4 * kc + 3]  : pwl[4 * kc + 1];
      }
    }

    // ---- PV: O^T += V^T * P^T ----
#pragma unroll
    for (int ht = 0; ht < 2; ++ht)
#pragma unroll
      for (int kc = 0; kc < 2; ++kc) {
        int vo = (ht * 32 + l31) * 40 + kc * 16 + h5 * 8;
        short8_t vfh = *reinterpret_cast<const short8_t*>(Vh + vo);
        short8_t vfl = *reinterpret_cast<const short8_t*>(Vl + vo);
#pragma unroll
        for (int qt = 0; qt < 2; ++qt) {
          union { int d[4]; short8_t s; } u1, u2;
#pragma unroll
          for (int d = 0; d < 4; ++d) {
            u1.d[d] = (qt == 0) ? pb0[kc][d] : pb1[kc][d];
            u2.d[d] = (qt == 0) ? plb0[kc][d] : plb1[kc][d];
          }
          ot[ht][qt] = MFMA32(vfh, u1.s, ot[ht][qt]);
          ot[ht][qt] = MFMA32(vfl, u1.s, ot[ht][qt]);
          ot[ht][qt] = MFMA32(vfh, u2.s, ot[ht][qt]);
        }
      }
  }

  // ---- 8-way stripe merge through LDS overlay ----
  __syncthreads();
  float* OT = (float*)smem;                  // [8][64][67] (pitch 67: no bank conflict)
  float* ML = (float*)(smem + 137216);       // [8][64][2]
#pragma unroll
  for (int ht = 0; ht < 2; ++ht)
#pragma unroll
    for (int qt = 0; qt < 2; ++qt)
#pragma unroll
      for (int r = 0; r < 16; ++r) {
        int h = ht * 32 + (r & 3) + 8 * (r >> 2) + 4 * h5;
        int q = qt * 32 + l31;
        OT[(ws * 64 + h) * 67 + q] = ot[ht][qt][r];
      }
  if (l < 32) {
#pragma unroll
    for (int qt = 0; qt < 2; ++qt) {
      int q = qt * 32 + l31;
      ML[(ws * 64 + q) * 2]     = mreg[qt];
      ML[(ws * 64 + q) * 2 + 1] = lreg[qt];
    }
  }
  __syncthreads();

  // final combine: thread -> h = tid&63, q-group = tid>>6
  {
    const int h = tid & 63;
    const int qg = tid >> 6;
#pragma unroll
    for (int i = 0; i < 8; ++i) {
      int q = qg * 8 + i;
      float M = ML[q * 2];
#pragma unroll
      for (int s = 1; s < 8; ++s) M = fmaxf(M, ML[(s * 64 + q) * 2]);
      float L = 0.f, acc2 = 0.f;
#pragma unroll
      for (int s = 0; s < 8; ++s) {
        float wgt = __builtin_amdgcn_exp2f((ML[(s * 64 + q) * 2] - M) * CE);
        L    += wgt * ML[(s * 64 + q) * 2 + 1];
        acc2 += wgt * OT[(s * 64 + h) * 67 + q];
      }
      out[((size_t)bb * 4096 + t0 + q) * 64 + h] = acc2 / L;
    }
  }
}

// ---------------------------------------------------------------------------
extern "C" void kernel_launch(void* const* d_in, const int* in_sizes, int n_in,
                              void* d_out, int out_size, void* d_ws, size_t ws_size,
                              hipStream_t stream) {
  const float* x  = (const float*)d_in[0];
  const float* Wq = (const float*)d_in[1];
  const float* Wk = (const float*)d_in[2];
  const float* Wv = (const float*)d_in[3];
  float* out = (float*)d_out;

  // workspace: 6 bf16 arrays of 16384*64 elements = 12 MB
  const size_t NE = (size_t)16384 * 64;
  unsigned short* qh  = (unsigned short*)d_ws;
  unsigned short* ql  = qh + NE;
  unsigned short* kh  = ql + NE;
  unsigned short* kl  = kh + NE;
  unsigned short* vth = kl + NE;   // V^T hi: [b*64+h][4096]
  unsigned short* vtl = vth + NE;  // V^T lo

  qkv_proj<<<256, 256, 0, stream>>>(x, Wq, Wk, Wv, qh, ql, kh, kl, vth, vtl);
  attn<<<256, 512, 0, stream>>>(qh, ql, kh, kl, vth, vtl, out);
}

// Round 3
// 237.000 us; speedup vs baseline: 1.0843x; 1.0843x over previous
//
#include <hip/hip_runtime.h>
#include <hip/hip_bf16.h>

// ---------------------------------------------------------------------------
// Causal single-head attention (B=4, T=4096, C=1024, H=64), fp32-accurate via
// split-bf16 (hi/lo) MFMA emulation. scale = HEAD_COUNT^-0.5 = 0.25.
//
//   wprep:      W -> W^T hi/lo bf16 [192][1024]
//   qkv_proj:   LDS-free GEMM; A-frags direct from x (fp32->hi/lo in reg),
//               B-frags direct from W^T. Outputs q,k [t][64] hi/lo and V in
//               fragment-ordered layout (vtidx) for coalesced PV loads.
//   attn:       LDS-free swapped-operand flash attention (S^T = K*Q^T via
//               mfma_32x32x16_bf16); q lane-local softmax; P^T in registers.
//               Grid balanced by causal key-slicing (640 blocks); 4-way
//               in-block stripe merge via LDS; partials to workspace.
//   attn_merge: combine 1-4 slice partials per (b, q-tile), write fp32 out.
// ---------------------------------------------------------------------------

typedef __attribute__((ext_vector_type(8))) short short8_t;   // 8 bf16
typedef __attribute__((ext_vector_type(4))) float f32x4;
typedef __attribute__((ext_vector_type(16))) float f32x16;

#define MFMA16(a, b, c) __builtin_amdgcn_mfma_f32_16x16x32_bf16((a), (b), (c), 0, 0, 0)
#define MFMA32(a, b, c) __builtin_amdgcn_mfma_f32_32x32x16_bf16((a), (b), (c), 0, 0, 0)

__device__ __forceinline__ unsigned short f2bf(float f) {
  union { float f; unsigned int u; } v; v.f = f;
  unsigned int u = v.u;
  u += 0x7FFFu + ((u >> 16) & 1u);   // RNE
  return (unsigned short)(u >> 16);
}
__device__ __forceinline__ float bf2f(unsigned short h) {
  union { unsigned int u; float f; } v; v.u = ((unsigned int)h) << 16;
  return v.f;
}

// V fragment-ordered layout: for kti=t>>5, ht=h>>5, kc=(t>>4)&1, h5=(t>>3)&1:
// contiguous 16B per lane l = h5*32 + (h&31), element e = t&7.
__device__ __forceinline__ size_t vtidx(int b, int t, int h) {
  return ((((((size_t)b * 128 + (t >> 5)) * 2 + (h >> 5)) * 2 + ((t >> 4) & 1)) * 2
           + ((t >> 3) & 1)) * 32 + (h & 31)) * 8 + (t & 7);
}

// ---------------------------------------------------------------------------
// wprep: W[1024][64] x3 fp32 -> W^T hi/lo bf16 [192][1024].
// Grid 128 x 192 thr; coalesced reads, 16B writes.
// ---------------------------------------------------------------------------
__global__ __launch_bounds__(192) void wprep(
    const float* __restrict__ Wq, const float* __restrict__ Wk,
    const float* __restrict__ Wv,
    unsigned short* __restrict__ wth, unsigned short* __restrict__ wtl)
{
  const int n  = threadIdx.x;        // 0..191 (global output col; wave-uniform mat)
  const int kb = blockIdx.x;         // 0..127 (k-block of 8)
  const float* W = (n < 64) ? Wq : (n < 128) ? Wk : Wv;
  const int cc = n & 63;
  union { unsigned short u[8]; short8_t s; } uh, ul;
#pragma unroll
  for (int j = 0; j < 8; ++j) {
    float f = W[(size_t)(kb * 8 + j) * 64 + cc];
    unsigned short h = f2bf(f);
    uh.u[j] = h;
    ul.u[j] = f2bf(f - bf2f(h));
  }
  *reinterpret_cast<short8_t*>(wth + (size_t)n * 1024 + kb * 8) = uh.s;
  *reinterpret_cast<short8_t*>(wtl + (size_t)n * 1024 + kb * 8) = ul.s;
}

// ---------------------------------------------------------------------------
// qkv_proj: x[16384,1024] fp32 @ W^T[192][1024] hi/lo, split (hh+hl+lh).
// Grid 512 x 256 thr (4 waves). Block = 32 rows x 192 cols; wave = 32r x 48c.
// No LDS, no barriers: A direct from x (cvt in reg), B direct from W^T.
// ---------------------------------------------------------------------------
__global__ __launch_bounds__(256) void qkv_proj(
    const float* __restrict__ x,
    const unsigned short* __restrict__ wth, const unsigned short* __restrict__ wtl,
    unsigned short* __restrict__ qh, unsigned short* __restrict__ ql,
    unsigned short* __restrict__ kh, unsigned short* __restrict__ kl,
    unsigned short* __restrict__ vth, unsigned short* __restrict__ vtl)
{
  const int tid  = threadIdx.x;
  const int wave = tid >> 6;
  const int lane = tid & 63;
  const int g    = lane >> 4;
  const int c    = lane & 15;
  const int m0   = blockIdx.x * 32;

  f32x4 acc[2][3];
#pragma unroll
  for (int m = 0; m < 2; ++m)
#pragma unroll
    for (int nn = 0; nn < 3; ++nn) acc[m][nn] = (f32x4){0.f, 0.f, 0.f, 0.f};

  for (int k0 = 0; k0 < 1024; k0 += 32) {
    short8_t a_h[2], a_l[2];
#pragma unroll
    for (int m = 0; m < 2; ++m) {
      const float* xp = x + (size_t)(m0 + m * 16 + c) * 1024 + k0 + g * 8;
      const float4 f0 = *reinterpret_cast<const float4*>(xp);
      const float4 f1 = *reinterpret_cast<const float4*>(xp + 4);
      union { unsigned short u[8]; short8_t s; } uh, ul;
#pragma unroll
      for (int j = 0; j < 4; ++j) {
        float fa = ((const float*)&f0)[j];
        unsigned short ha = f2bf(fa);
        uh.u[j] = ha; ul.u[j] = f2bf(fa - bf2f(ha));
        float fb = ((const float*)&f1)[j];
        unsigned short hb = f2bf(fb);
        uh.u[4 + j] = hb; ul.u[4 + j] = f2bf(fb - bf2f(hb));
      }
      a_h[m] = uh.s; a_l[m] = ul.s;
    }
#pragma unroll
    for (int nn = 0; nn < 3; ++nn) {
      const int nt = wave * 3 + nn;
      const size_t bo = (size_t)(nt * 16 + c) * 1024 + k0 + g * 8;
      const short8_t b_h = *reinterpret_cast<const short8_t*>(wth + bo);
      const short8_t b_l = *reinterpret_cast<const short8_t*>(wtl + bo);
#pragma unroll
      for (int m = 0; m < 2; ++m) {
        acc[m][nn] = MFMA16(a_h[m], b_h, acc[m][nn]);
        acc[m][nn] = MFMA16(a_h[m], b_l, acc[m][nn]);
        acc[m][nn] = MFMA16(a_l[m], b_h, acc[m][nn]);
      }
    }
  }

  // epilogue: C/D layout col=lane&15, row=g*4+r
#pragma unroll
  for (int m = 0; m < 2; ++m) {
#pragma unroll
    for (int nn = 0; nn < 3; ++nn) {
      const int nt  = wave * 3 + nn;
      const int col = nt * 16 + c;       // 0..191
      const int mat = col >> 6;          // uniform per nn
      const int cm  = col & 63;
#pragma unroll
      for (int r = 0; r < 4; ++r) {
        float f = acc[m][nn][r];
        int row = m0 + m * 16 + g * 4 + r;
        unsigned short h  = f2bf(f);
        unsigned short lo = f2bf(f - bf2f(h));
        if (mat == 0)      { size_t i = (size_t)row * 64 + cm; qh[i] = h; ql[i] = lo; }
        else if (mat == 1) { size_t i = (size_t)row * 64 + cm; kh[i] = h; kl[i] = lo; }
        else {
          int bb = row >> 12, t = row & 4095;
          size_t i = vtidx(bb, t, cm);
          vth[i] = h; vtl[i] = lo;
        }
      }
    }
  }
}

// ---------------------------------------------------------------------------
// attn: grid 640 = 4 b x 160 (jt,slice). Block 256 thr / 4 waves; wave ws
// takes ktis k0t+ws, +4, ... Per wave: 64 q in regs, K/V frags direct from
// global (coalesced), P^T in registers. LDS only for final 4-way merge.
// D-layout (32x32): col = lane&31, row = (r&3)+8*(r>>2)+4*(lane>>5).
// ---------------------------------------------------------------------------
#define MASKVAL (-3.0e38f)
#define MINIT   (-1.0e30f)

__global__ __launch_bounds__(256, 2) void attn(
    const unsigned short* __restrict__ qh, const unsigned short* __restrict__ ql,
    const unsigned short* __restrict__ kh, const unsigned short* __restrict__ kl,
    const unsigned short* __restrict__ vth, const unsigned short* __restrict__ vtl,
    float* __restrict__ Opart, float* __restrict__ MLpart)
{
  __shared__ alignas(16) unsigned char smem[70656];   // OT[4][64][67] + ML[4][64][2]

  const int tid = threadIdx.x;
  const int ws  = tid >> 6;
  const int l   = tid & 63;
  const int h5  = l >> 5;
  const int l31 = l & 31;

  // block -> (b, jt, slice, nsl); nsl = quartile(jt)+1
  const int bidb = blockIdx.x;
  const int bb   = bidb / 160;
  const int s    = bidb % 160;
  int jt, slice, nsl;
  if (s < 16)      { jt = s;                         slice = 0;                nsl = 1; }
  else if (s < 48) { int i = s - 16; jt = 16 + (i >> 1); slice = i & 1;        nsl = 2; }
  else if (s < 96) { int i = s - 48; jt = 32 + i / 3;    slice = i - 3 * (jt - 32); nsl = 3; }
  else             { int i = s - 96; jt = 48 + (i >> 2); slice = i & 3;        nsl = 4; }
  const int t0    = jt * 64;
  const int total = 2 * (jt + 1);                  // ktis for this q-tile
  const int k0t   = (slice * total) / nsl;
  const int k1t   = ((slice + 1) * total) / nsl;

  const float CE = 0.36067376022224085f;           // 0.25 * log2(e)

  // Q^T B-fragments in registers (col = q = t0 + qt*32 + l31)
  short8_t qf_h[2][4], qf_l[2][4];
#pragma unroll
  for (int qt = 0; qt < 2; ++qt)
#pragma unroll
    for (int cc = 0; cc < 4; ++cc) {
      size_t off = ((size_t)(bb * 4096 + t0 + qt * 32 + l31)) * 64 + cc * 16 + h5 * 8;
      qf_h[qt][cc] = *reinterpret_cast<const short8_t*>(qh + off);
      qf_l[qt][cc] = *reinterpret_cast<const short8_t*>(ql + off);
    }

  f32x16 ot[2][2];
#pragma unroll
  for (int a = 0; a < 2; ++a)
#pragma unroll
    for (int b2 = 0; b2 < 2; ++b2)
#pragma unroll
      for (int r = 0; r < 16; ++r) ot[a][b2][r] = 0.f;
  float mreg[2] = {MINIT, MINIT};
  float lreg[2] = {0.f, 0.f};

  for (int kti = k0t + ws; kti < k1t; kti += 4) {
    const int s0 = kti * 32;

    // K A-fragments direct from global (fully coalesced: 1KB/instr)
    short8_t kf_h[4], kf_l[4];
    const size_t krow = ((size_t)(bb * 4096 + s0 + l31)) * 64 + h5 * 8;
#pragma unroll
    for (int cc = 0; cc < 4; ++cc) {
      kf_h[cc] = *reinterpret_cast<const short8_t*>(kh + krow + cc * 16);
      kf_l[cc] = *reinterpret_cast<const short8_t*>(kl + krow + cc * 16);
    }

    short8_t pfh[2][2], pfl[2][2];

#pragma unroll
    for (int qt = 0; qt < 2; ++qt) {
      if (s0 > t0 + qt * 32 + 31) {                // tile fully masked for this qt
        union { int d[4]; short8_t s8; } z;
        z.d[0] = z.d[1] = z.d[2] = z.d[3] = 0;
        pfh[qt][0] = z.s8; pfh[qt][1] = z.s8;
        pfl[qt][0] = z.s8; pfl[qt][1] = z.s8;
        continue;
      }

      f32x16 st;
#pragma unroll
      for (int r = 0; r < 16; ++r) st[r] = 0.f;
#pragma unroll
      for (int cc = 0; cc < 4; ++cc) {
        st = MFMA32(kf_h[cc], qf_h[qt][cc], st);
        st = MFMA32(kf_h[cc], qf_l[qt][cc], st);
        st = MFMA32(kf_l[cc], qf_h[qt][cc], st);
      }

      if (s0 + 31 > t0 + qt * 32) {                // causal mask (diagonal tiles)
        int qg = t0 + qt * 32 + l31;
#pragma unroll
        for (int r = 0; r < 16; ++r) {
          int keyg = s0 + (r & 3) + 8 * (r >> 2) + 4 * h5;
          if (keyg > qg) st[r] = MASKVAL;
        }
      }

      // online softmax: q lane-local -> in-lane reduce + one half-exchange
      float pm = st[0];
#pragma unroll
      for (int r = 1; r < 16; ++r) pm = fmaxf(pm, st[r]);
      pm = fmaxf(pm, __shfl_xor(pm, 32));
      float mnew = fmaxf(mreg[qt], pm);
      float fs = __builtin_amdgcn_exp2f((mreg[qt] - mnew) * CE);
      mreg[qt] = mnew;
      lreg[qt] *= fs;
#pragma unroll
      for (int ht = 0; ht < 2; ++ht) ot[ht][qt] *= fs;

      float p[16]; float rs = 0.f;
#pragma unroll
      for (int r = 0; r < 16; ++r) {
        p[r] = __builtin_amdgcn_exp2f((st[r] - mnew) * CE);
        rs += p[r];
      }
      rs += __shfl_xor(rs, 32);
      lreg[qt] += rs;

      // pack P hi/lo into key-pair dwords; exchange halves via shfl
      int w[8], wl[8], pw[8], pwl[8];
#pragma unroll
      for (int i = 0; i < 8; ++i) {
        unsigned short b0 = f2bf(p[2 * i]), b1 = f2bf(p[2 * i + 1]);
        w[i] = (int)((unsigned)b0 | ((unsigned)b1 << 16));
        float l0 = p[2 * i] - bf2f(b0), l1 = p[2 * i + 1] - bf2f(b1);
        wl[i] = (int)((unsigned)f2bf(l0) | ((unsigned)f2bf(l1) << 16));
      }
#pragma unroll
      for (int i = 0; i < 8; ++i) {
        pw[i]  = __shfl_xor(w[i], 32);
        pwl[i] = __shfl_xor(wl[i], 32);
      }
#pragma unroll
      for (int kc = 0; kc < 2; ++kc) {
        union { int d[4]; short8_t s8; } uh2, ul2;
        uh2.d[0] = h5 ? pw[4 * kc + 2]  : w[4 * kc];
        uh2.d[1] = h5 ? pw[4 * kc + 3]  : w[4 * kc + 1];
        uh2.d[2] = h5 ? w[4 * kc + 2]   : pw[4 * kc];
        uh2.d[3] = h5 ? w[4 * kc + 3]   : pw[4 * kc + 1];
        ul2.d[0] = h5 ? pwl[4 * kc + 2] : wl[4 * kc];
        ul2.d[1] = h5 ? pwl[4 * kc + 3] : wl[4 * kc + 1];
        ul2.d[2] = h5 ? wl[4 * kc + 2]  : pwl[4 * kc];
        ul2.d[3] = h5 ? wl[4 * kc + 3]  : pwl[4 * kc + 1];
        pfh[qt][kc] = uh2.s8;
        pfl[qt][kc] = ul2.s8;
      }
    }

    // PV: O^T += V^T * P^T ; V-frags fragment-ordered (coalesced 1KB/instr)
#pragma unroll
    for (int ht = 0; ht < 2; ++ht)
#pragma unroll
      for (int kc = 0; kc < 2; ++kc) {
        const size_t vbase =
            ((size_t)(((bb * 128 + kti) * 2 + ht) * 2 + kc)) * 512 + (size_t)l * 8;
        const short8_t vfh = *reinterpret_cast<const short8_t*>(vth + vbase);
        const short8_t vfl = *reinterpret_cast<const short8_t*>(vtl + vbase);
#pragma unroll
        for (int qt = 0; qt < 2; ++qt) {
          ot[ht][qt] = MFMA32(vfh, pfh[qt][kc], ot[ht][qt]);
          ot[ht][qt] = MFMA32(vfl, pfh[qt][kc], ot[ht][qt]);
          ot[ht][qt] = MFMA32(vfh, pfl[qt][kc], ot[ht][qt]);
        }
      }
  }

  // ---- in-block 4-way stripe merge through LDS ----
  float* OT = (float*)smem;                  // [4][64][67]
  float* ML = (float*)(smem + 68608);        // [4][64][2]
#pragma unroll
  for (int ht = 0; ht < 2; ++ht)
#pragma unroll
    for (int qt = 0; qt < 2; ++qt)
#pragma unroll
      for (int r = 0; r < 16; ++r) {
        int hrow = ht * 32 + (r & 3) + 8 * (r >> 2) + 4 * h5;
        int q = qt * 32 + l31;
        OT[(ws * 64 + hrow) * 67 + q] = ot[ht][qt][r];
      }
  if (l < 32) {
#pragma unroll
    for (int qt = 0; qt < 2; ++qt) {
      int q = qt * 32 + l31;
      ML[(ws * 64 + q) * 2]     = mreg[qt];
      ML[(ws * 64 + q) * 2 + 1] = lreg[qt];
    }
  }
  __syncthreads();

  {
    const int h  = tid & 63;
    const int qg = tid >> 6;
#pragma unroll
    for (int i = 0; i < 16; ++i) {
      int q = qg * 16 + i;
      float M = ML[q * 2];
#pragma unroll
      for (int s2 = 1; s2 < 4; ++s2) M = fmaxf(M, ML[(s2 * 64 + q) * 2]);
      float L = 0.f, A = 0.f;
#pragma unroll
      for (int s2 = 0; s2 < 4; ++s2) {
        float wgt = __builtin_amdgcn_exp2f((ML[(s2 * 64 + q) * 2] - M) * CE);
        L += wgt * ML[(s2 * 64 + q) * 2 + 1];
        A += wgt * OT[(s2 * 64 + h) * 67 + q];
      }
      Opart[((size_t)bidb * 64 + q) * 64 + h] = A;
      if (h == 0) MLpart[((size_t)bidb * 64 + q) * 2]     = M;
      if (h == 1) MLpart[((size_t)bidb * 64 + q) * 2 + 1] = L;
    }
  }
}

// ---------------------------------------------------------------------------
// attn_merge: combine the 1-4 slice partials of each (b, jt); write fp32 out.
// Grid 256 = (b, jt); 256 thr: q = t>>2, h-group = (t&3)*16.
// ---------------------------------------------------------------------------
__global__ __launch_bounds__(256) void attn_merge(
    const float* __restrict__ Opart, const float* __restrict__ MLpart,
    float* __restrict__ out)
{
  const int bid = blockIdx.x;
  const int bb = bid >> 6, jt = bid & 63;
  const int nsl = 1 + (jt >= 16) + (jt >= 32) + (jt >= 48);
  const int off = (jt < 16) ? jt
                : (jt < 32) ? 16 + 2 * (jt - 16)
                : (jt < 48) ? 48 + 3 * (jt - 32)
                :             96 + 4 * (jt - 48);
  const int pid0 = bb * 160 + off;
  const int t = threadIdx.x;
  const int q = t >> 2;
  const int hg = t & 3;
  const float CE = 0.36067376022224085f;

  float M = MLpart[((size_t)pid0 * 64 + q) * 2];
  for (int s2 = 1; s2 < nsl; ++s2)
    M = fmaxf(M, MLpart[((size_t)(pid0 + s2) * 64 + q) * 2]);

  float L = 0.f;
  float a[16];
#pragma unroll
  for (int j = 0; j < 16; ++j) a[j] = 0.f;

  for (int s2 = 0; s2 < nsl; ++s2) {
    size_t mlb = ((size_t)(pid0 + s2) * 64 + q) * 2;
    float w = __builtin_amdgcn_exp2f((MLpart[mlb] - M) * CE);
    L += w * MLpart[mlb + 1];
    const float* op = Opart + ((size_t)(pid0 + s2) * 64 + q) * 64 + hg * 16;
#pragma unroll
    for (int j = 0; j < 4; ++j) {
      float4 v4 = *reinterpret_cast<const float4*>(op + j * 4);
      a[j * 4 + 0] += w * v4.x; a[j * 4 + 1] += w * v4.y;
      a[j * 4 + 2] += w * v4.z; a[j * 4 + 3] += w * v4.w;
    }
  }

  const float inv = 1.f / L;
  float* po = out + ((size_t)bb * 4096 + jt * 64 + q) * 64 + hg * 16;
#pragma unroll
  for (int j = 0; j < 4; ++j) {
    float4 v4 = { a[j * 4] * inv, a[j * 4 + 1] * inv,
                  a[j * 4 + 2] * inv, a[j * 4 + 3] * inv };
    *reinterpret_cast<float4*>(po + j * 4) = v4;
  }
}

// ---------------------------------------------------------------------------
extern "C" void kernel_launch(void* const* d_in, const int* in_sizes, int n_in,
                              void* d_out, int out_size, void* d_ws, size_t ws_size,
                              hipStream_t stream) {
  const float* x  = (const float*)d_in[0];
  const float* Wq = (const float*)d_in[1];
  const float* Wk = (const float*)d_in[2];
  const float* Wv = (const float*)d_in[3];
  float* out = (float*)d_out;

  // workspace layout (bytes):
  //   6 x NE ushort  : qh, ql, kh, kl, vth, vtl           (12.58 MB)
  //   2 x 196608 us  : wth, wtl (W^T hi/lo)               ( 0.79 MB)
  //   640*64*64 f32  : Opart                              (10.49 MB)
  //   640*64*2  f32  : MLpart                             ( 0.33 MB)
  const size_t NE = (size_t)16384 * 64;
  unsigned short* qh  = (unsigned short*)d_ws;
  unsigned short* ql  = qh + NE;
  unsigned short* kh  = ql + NE;
  unsigned short* kl  = kh + NE;
  unsigned short* vth = kl + NE;
  unsigned short* vtl = vth + NE;
  unsigned short* wth = vtl + NE;
  unsigned short* wtl = wth + (size_t)192 * 1024;
  float* Opart  = (float*)(wtl + (size_t)192 * 1024);
  float* MLpart = Opart + (size_t)640 * 64 * 64;

  wprep<<<128, 192, 0, stream>>>(Wq, Wk, Wv, wth, wtl);
  qkv_proj<<<512, 256, 0, stream>>>(x, wth, wtl, qh, ql, kh, kl, vth, vtl);
  attn<<<640, 256, 0, stream>>>(qh, ql, kh, kl, vth, vtl, Opart, MLpart);
  attn_merge<<<256, 256, 0, stream>>>(Opart, MLpart, out);
}

// Round 5
// 229.989 us; speedup vs baseline: 1.1173x; 1.0305x over previous
//
#include <hip/hip_runtime.h>
#include <hip/hip_bf16.h>

// ---------------------------------------------------------------------------
// Causal single-head attention (B=4, T=4096, C=1024, H=64), fp32-accurate via
// split-bf16 (hi/lo) MFMA emulation. scale = HEAD_COUNT^-0.5 = 0.25.
//
//   wprep:      W -> W^T hi/lo bf16 [192][1024]
//   qkv_proj:   LDS-free GEMM, depth-1 register ping-pong pipeline.
//   attn:       LDS-free swapped-operand flash attention, XCD-swizzled grid,
//               setprio'd MFMA clusters, batched V-loads.
//   attn_merge: combine 1-4 slice partials per (b, q-tile), write fp32 out.
// ---------------------------------------------------------------------------

typedef __attribute__((ext_vector_type(8))) short short8_t;   // 8 bf16
typedef __attribute__((ext_vector_type(4))) float f32x4;
typedef __attribute__((ext_vector_type(16))) float f32x16;

#define MFMA16(a, b, c) __builtin_amdgcn_mfma_f32_16x16x32_bf16((a), (b), (c), 0, 0, 0)
#define MFMA32(a, b, c) __builtin_amdgcn_mfma_f32_32x32x16_bf16((a), (b), (c), 0, 0, 0)

__device__ __forceinline__ unsigned short f2bf(float f) {
  union { float f; unsigned int u; } v; v.f = f;
  unsigned int u = v.u;
  u += 0x7FFFu + ((u >> 16) & 1u);   // RNE
  return (unsigned short)(u >> 16);
}
__device__ __forceinline__ float bf2f(unsigned short h) {
  union { unsigned int u; float f; } v; v.u = ((unsigned int)h) << 16;
  return v.f;
}

// V fragment-ordered layout (coalesced PV loads)
__device__ __forceinline__ size_t vtidx(int b, int t, int h) {
  return ((((((size_t)b * 128 + (t >> 5)) * 2 + (h >> 5)) * 2 + ((t >> 4) & 1)) * 2
           + ((t >> 3) & 1)) * 32 + (h & 31)) * 8 + (t & 7);
}

// ---------------------------------------------------------------------------
// wprep: W[1024][64] x3 fp32 -> W^T hi/lo bf16 [192][1024].
// ---------------------------------------------------------------------------
__global__ __launch_bounds__(192) void wprep(
    const float* __restrict__ Wq, const float* __restrict__ Wk,
    const float* __restrict__ Wv,
    unsigned short* __restrict__ wth, unsigned short* __restrict__ wtl)
{
  const int n  = threadIdx.x;
  const int kb = blockIdx.x;
  const float* W = (n < 64) ? Wq : (n < 128) ? Wk : Wv;
  const int cc = n & 63;
  union { unsigned short u[8]; short8_t s; } uh, ul;
#pragma unroll
  for (int j = 0; j < 8; ++j) {
    float f = W[(size_t)(kb * 8 + j) * 64 + cc];
    unsigned short h = f2bf(f);
    uh.u[j] = h;
    ul.u[j] = f2bf(f - bf2f(h));
  }
  *reinterpret_cast<short8_t*>(wth + (size_t)n * 1024 + kb * 8) = uh.s;
  *reinterpret_cast<short8_t*>(wtl + (size_t)n * 1024 + kb * 8) = ul.s;
}

// ---------------------------------------------------------------------------
// qkv_proj: x[16384,1024] fp32 @ W^T[192][1024] hi/lo, split (hh+hl+lh).
// Grid 512 x 256 thr (4 waves). Block = 32 rows x 192 cols; wave = 32r x 48c.
// Depth-1 register ping-pong: loads for step k+32 issue before MFMAs of k.
// ---------------------------------------------------------------------------
__global__ __launch_bounds__(256, 2) void qkv_proj(
    const float* __restrict__ x,
    const unsigned short* __restrict__ wth, const unsigned short* __restrict__ wtl,
    unsigned short* __restrict__ qh, unsigned short* __restrict__ ql,
    unsigned short* __restrict__ kh, unsigned short* __restrict__ kl,
    unsigned short* __restrict__ vth, unsigned short* __restrict__ vtl)
{
  const int tid  = threadIdx.x;
  const int wave = tid >> 6;
  const int lane = tid & 63;
  const int g    = lane >> 4;
  const int c    = lane & 15;
  const int m0   = blockIdx.x * 32;

  const float* xb = x + (size_t)(m0 + c) * 1024 + g * 8;
  const unsigned short* bhb = wth + (size_t)(wave * 48 + c) * 1024 + g * 8;
  const unsigned short* blb = wtl + (size_t)(wave * 48 + c) * 1024 + g * 8;

  f32x4 acc[2][3];
#pragma unroll
  for (int m = 0; m < 2; ++m)
#pragma unroll
    for (int nn = 0; nn < 3; ++nn) acc[m][nn] = (f32x4){0.f, 0.f, 0.f, 0.f};

  float4 A0[4], A1[4];                 // [m*2+half] raw x
  short8_t B0h[3], B0l[3], B1h[3], B1l[3];

#define LOADA(buf, kk) do {                                                  \
    _Pragma("unroll") for (int m_ = 0; m_ < 2; ++m_) {                       \
      const float* p_ = xb + (size_t)m_ * 16384 + (kk);                      \
      buf[m_ * 2]     = *reinterpret_cast<const float4*>(p_);                \
      buf[m_ * 2 + 1] = *reinterpret_cast<const float4*>(p_ + 4);            \
    } } while (0)
#define LOADB(bh, bl, kk) do {                                               \
    _Pragma("unroll") for (int nn_ = 0; nn_ < 3; ++nn_) {                    \
      const size_t bo_ = (size_t)nn_ * 16384 + (kk);                         \
      bh[nn_] = *reinterpret_cast<const short8_t*>(bhb + bo_);               \
      bl[nn_] = *reinterpret_cast<const short8_t*>(blb + bo_);               \
    } } while (0)
#define STEP(Abuf, Bh, Bl) do {                                              \
    short8_t a_h[2], a_l[2];                                                 \
    _Pragma("unroll") for (int m_ = 0; m_ < 2; ++m_) {                       \
      union { unsigned short u[8]; short8_t s; } uh_, ul_;                   \
      _Pragma("unroll") for (int hf_ = 0; hf_ < 2; ++hf_) {                  \
        const float4 f_ = Abuf[m_ * 2 + hf_];                                \
        _Pragma("unroll") for (int j_ = 0; j_ < 4; ++j_) {                   \
          float fv_ = ((const float*)&f_)[j_];                               \
          unsigned short hh_ = f2bf(fv_);                                    \
          uh_.u[hf_ * 4 + j_] = hh_;                                         \
          ul_.u[hf_ * 4 + j_] = f2bf(fv_ - bf2f(hh_));                       \
        } }                                                                  \
      a_h[m_] = uh_.s; a_l[m_] = ul_.s; }                                    \
    _Pragma("unroll") for (int nn_ = 0; nn_ < 3; ++nn_)                      \
      _Pragma("unroll") for (int m_ = 0; m_ < 2; ++m_) {                     \
        acc[m_][nn_] = MFMA16(a_h[m_], Bh[nn_], acc[m_][nn_]);               \
        acc[m_][nn_] = MFMA16(a_h[m_], Bl[nn_], acc[m_][nn_]);               \
        acc[m_][nn_] = MFMA16(a_l[m_], Bh[nn_], acc[m_][nn_]);               \
      } } while (0)

  LOADA(A0, 0); LOADB(B0h, B0l, 0);
  for (int k0 = 0; k0 < 1024; k0 += 64) {
    LOADA(A1, k0 + 32); LOADB(B1h, B1l, k0 + 32);
    STEP(A0, B0h, B0l);
    const int kn = (k0 + 64 < 1024) ? k0 + 64 : 0;   // clamped (safe dummy)
    LOADA(A0, kn); LOADB(B0h, B0l, kn);
    STEP(A1, B1h, B1l);
  }
#undef LOADA
#undef LOADB
#undef STEP

  // epilogue: C/D layout col=lane&15, row=g*4+r
#pragma unroll
  for (int m = 0; m < 2; ++m) {
#pragma unroll
    for (int nn = 0; nn < 3; ++nn) {
      const int nt  = wave * 3 + nn;
      const int col = nt * 16 + c;
      const int mat = col >> 6;
      const int cm  = col & 63;
#pragma unroll
      for (int r = 0; r < 4; ++r) {
        float f = acc[m][nn][r];
        int row = m0 + m * 16 + g * 4 + r;
        unsigned short h  = f2bf(f);
        unsigned short lo = f2bf(f - bf2f(h));
        if (mat == 0)      { size_t i = (size_t)row * 64 + cm; qh[i] = h; ql[i] = lo; }
        else if (mat == 1) { size_t i = (size_t)row * 64 + cm; kh[i] = h; kl[i] = lo; }
        else {
          int bb = row >> 12, t = row & 4095;
          size_t i = vtidx(bb, t, cm);
          vth[i] = h; vtl[i] = lo;
        }
      }
    }
  }
}

// ---------------------------------------------------------------------------
// attn: 640 blocks, XCD-swizzled so each XCD's L2 serves one batch b.
// Block 256 thr / 4 waves; wave ws strides 32-key tiles. Q in regs, K/V
// direct-global coalesced, P^T in registers. LDS only for 4-way merge.
// D-layout (32x32): col = lane&31, row = (r&3)+8*(r>>2)+4*(lane>>5).
// ---------------------------------------------------------------------------
#define MASKVAL (-3.0e38f)
#define MINIT   (-1.0e30f)

__global__ __launch_bounds__(256, 2) void attn(
    const unsigned short* __restrict__ qh, const unsigned short* __restrict__ ql,
    const unsigned short* __restrict__ kh, const unsigned short* __restrict__ kl,
    const unsigned short* __restrict__ vth, const unsigned short* __restrict__ vtl,
    float* __restrict__ Opart, float* __restrict__ MLpart)
{
  __shared__ alignas(16) unsigned char smem[70656];   // OT[4][64][67] + ML[4][64][2]

  const int tid = threadIdx.x;
  const int ws  = tid >> 6;
  const int l   = tid & 63;
  const int h5  = l >> 5;
  const int l31 = l & 31;

  // XCD swizzle: xcd = blockIdx%8 (HW round-robin); XCDs {2b,2b+1} own batch b.
  const int bid0 = blockIdx.x;
  const int xcd  = bid0 & 7;
  const int bb   = xcd >> 1;
  const int s    = ((bid0 >> 3) << 1) | (xcd & 1);   // 0..159
  const int bidb = bb * 160 + s;                     // logical id (Opart index)

  int jt, slice, nsl;
  if (s < 16)      { jt = s;                             slice = 0;                nsl = 1; }
  else if (s < 48) { int i = s - 16; jt = 16 + (i >> 1); slice = i & 1;            nsl = 2; }
  else if (s < 96) { int i = s - 48; jt = 32 + i / 3;    slice = i - 3 * (jt - 32); nsl = 3; }
  else             { int i = s - 96; jt = 48 + (i >> 2); slice = i & 3;            nsl = 4; }
  const int t0    = jt * 64;
  const int total = 2 * (jt + 1);
  const int k0t   = (slice * total) / nsl;
  const int k1t   = ((slice + 1) * total) / nsl;

  const float CE = 0.36067376022224085f;   // 0.25 * log2(e)

  // Q^T B-fragments in registers
  short8_t qf_h[2][4], qf_l[2][4];
#pragma unroll
  for (int qt = 0; qt < 2; ++qt)
#pragma unroll
    for (int cc = 0; cc < 4; ++cc) {
      size_t off = ((size_t)(bb * 4096 + t0 + qt * 32 + l31)) * 64 + cc * 16 + h5 * 8;
      qf_h[qt][cc] = *reinterpret_cast<const short8_t*>(qh + off);
      qf_l[qt][cc] = *reinterpret_cast<const short8_t*>(ql + off);
    }

  f32x16 ot[2][2];
#pragma unroll
  for (int a = 0; a < 2; ++a)
#pragma unroll
    for (int b2 = 0; b2 < 2; ++b2)
#pragma unroll
      for (int r = 0; r < 16; ++r) ot[a][b2][r] = 0.f;
  float mreg[2] = {MINIT, MINIT};
  float lreg[2] = {0.f, 0.f};

  for (int kti = k0t + ws; kti < k1t; kti += 4) {
    const int s0 = kti * 32;

    // K A-fragments direct from global (coalesced)
    short8_t kf_h[4], kf_l[4];
    const size_t krow = ((size_t)(bb * 4096 + s0 + l31)) * 64 + h5 * 8;
#pragma unroll
    for (int cc = 0; cc < 4; ++cc) {
      kf_h[cc] = *reinterpret_cast<const short8_t*>(kh + krow + cc * 16);
      kf_l[cc] = *reinterpret_cast<const short8_t*>(kl + krow + cc * 16);
    }

    short8_t pfh[2][2], pfl[2][2];

#pragma unroll
    for (int qt = 0; qt < 2; ++qt) {
      if (s0 > t0 + qt * 32 + 31) {
        union { int d[4]; short8_t s8; } z;
        z.d[0] = z.d[1] = z.d[2] = z.d[3] = 0;
        pfh[qt][0] = z.s8; pfh[qt][1] = z.s8;
        pfl[qt][0] = z.s8; pfl[qt][1] = z.s8;
        continue;
      }

      f32x16 st;
#pragma unroll
      for (int r = 0; r < 16; ++r) st[r] = 0.f;
      __builtin_amdgcn_s_setprio(1);
#pragma unroll
      for (int cc = 0; cc < 4; ++cc) {
        st = MFMA32(kf_h[cc], qf_h[qt][cc], st);
        st = MFMA32(kf_h[cc], qf_l[qt][cc], st);
        st = MFMA32(kf_l[cc], qf_h[qt][cc], st);
      }
      __builtin_amdgcn_s_setprio(0);

      if (s0 + 31 > t0 + qt * 32) {
        int qg = t0 + qt * 32 + l31;
#pragma unroll
        for (int r = 0; r < 16; ++r) {
          int keyg = s0 + (r & 3) + 8 * (r >> 2) + 4 * h5;
          if (keyg > qg) st[r] = MASKVAL;
        }
      }

      float pm = st[0];
#pragma unroll
      for (int r = 1; r < 16; ++r) pm = fmaxf(pm, st[r]);
      pm = fmaxf(pm, __shfl_xor(pm, 32));
      float mnew = fmaxf(mreg[qt], pm);
      float fs = __builtin_amdgcn_exp2f((mreg[qt] - mnew) * CE);
      mreg[qt] = mnew;
      lreg[qt] *= fs;
#pragma unroll
      for (int ht = 0; ht < 2; ++ht) ot[ht][qt] *= fs;

      float p[16]; float rs = 0.f;
#pragma unroll
      for (int r = 0; r < 16; ++r) {
        p[r] = __builtin_amdgcn_exp2f((st[r] - mnew) * CE);
        rs += p[r];
      }
      rs += __shfl_xor(rs, 32);
      lreg[qt] += rs;

      int w[8], wl[8], pw[8], pwl[8];
#pragma unroll
      for (int i = 0; i < 8; ++i) {
        unsigned short b0 = f2bf(p[2 * i]), b1 = f2bf(p[2 * i + 1]);
        w[i] = (int)((unsigned)b0 | ((unsigned)b1 << 16));
        float l0 = p[2 * i] - bf2f(b0), l1 = p[2 * i + 1] - bf2f(b1);
        wl[i] = (int)((unsigned)f2bf(l0) | ((unsigned)f2bf(l1) << 16));
      }
#pragma unroll
      for (int i = 0; i < 8; ++i) {
        pw[i]  = __shfl_xor(w[i], 32);
        pwl[i] = __shfl_xor(wl[i], 32);
      }
#pragma unroll
      for (int kc = 0; kc < 2; ++kc) {
        union { int d[4]; short8_t s8; } uh2, ul2;
        uh2.d[0] = h5 ? pw[4 * kc + 2]  : w[4 * kc];
        uh2.d[1] = h5 ? pw[4 * kc + 3]  : w[4 * kc + 1];
        uh2.d[2] = h5 ? w[4 * kc + 2]   : pw[4 * kc];
        uh2.d[3] = h5 ? w[4 * kc + 3]   : pw[4 * kc + 1];
        ul2.d[0] = h5 ? pwl[4 * kc + 2] : wl[4 * kc];
        ul2.d[1] = h5 ? pwl[4 * kc + 3] : wl[4 * kc + 1];
        ul2.d[2] = h5 ? wl[4 * kc + 2]  : pwl[4 * kc];
        ul2.d[3] = h5 ? wl[4 * kc + 3]  : pwl[4 * kc + 1];
        pfh[qt][kc] = uh2.s8;
        pfl[qt][kc] = ul2.s8;
      }
    }

    // batched V-loads (fragment-ordered, coalesced), then PV cluster
    short8_t vfh[2][2], vfl[2][2];
#pragma unroll
    for (int ht = 0; ht < 2; ++ht)
#pragma unroll
      for (int kc = 0; kc < 2; ++kc) {
        const size_t vbase =
            ((size_t)(((bb * 128 + kti) * 2 + ht) * 2 + kc)) * 512 + (size_t)l * 8;
        vfh[ht][kc] = *reinterpret_cast<const short8_t*>(vth + vbase);
        vfl[ht][kc] = *reinterpret_cast<const short8_t*>(vtl + vbase);
      }

    __builtin_amdgcn_s_setprio(1);
#pragma unroll
    for (int ht = 0; ht < 2; ++ht)
#pragma unroll
      for (int kc = 0; kc < 2; ++kc)
#pragma unroll
        for (int qt = 0; qt < 2; ++qt) {
          ot[ht][qt] = MFMA32(vfh[ht][kc], pfh[qt][kc], ot[ht][qt]);
          ot[ht][qt] = MFMA32(vfl[ht][kc], pfh[qt][kc], ot[ht][qt]);
          ot[ht][qt] = MFMA32(vfh[ht][kc], pfl[qt][kc], ot[ht][qt]);
        }
    __builtin_amdgcn_s_setprio(0);
  }

  // ---- in-block 4-way stripe merge through LDS ----
  float* OT = (float*)smem;                  // [4][64][67]
  float* ML = (float*)(smem + 68608);        // [4][64][2]
#pragma unroll
  for (int ht = 0; ht < 2; ++ht)
#pragma unroll
    for (int qt = 0; qt < 2; ++qt)
#pragma unroll
      for (int r = 0; r < 16; ++r) {
        int hrow = ht * 32 + (r & 3) + 8 * (r >> 2) + 4 * h5;
        int q = qt * 32 + l31;
        OT[(ws * 64 + hrow) * 67 + q] = ot[ht][qt][r];
      }
  if (l < 32) {
#pragma unroll
    for (int qt = 0; qt < 2; ++qt) {
      int q = qt * 32 + l31;
      ML[(ws * 64 + q) * 2]     = mreg[qt];
      ML[(ws * 64 + q) * 2 + 1] = lreg[qt];
    }
  }
  __syncthreads();

  {
    const int h  = tid & 63;
    const int qg = tid >> 6;
#pragma unroll
    for (int i = 0; i < 16; ++i) {
      int q = qg * 16 + i;
      float M = ML[q * 2];
#pragma unroll
      for (int s2 = 1; s2 < 4; ++s2) M = fmaxf(M, ML[(s2 * 64 + q) * 2]);
      float L = 0.f, A = 0.f;
#pragma unroll
      for (int s2 = 0; s2 < 4; ++s2) {
        float wgt = __builtin_amdgcn_exp2f((ML[(s2 * 64 + q) * 2] - M) * CE);
        L += wgt * ML[(s2 * 64 + q) * 2 + 1];
        A += wgt * OT[(s2 * 64 + h) * 67 + q];
      }
      Opart[((size_t)bidb * 64 + q) * 64 + h] = A;
      if (h == 0) MLpart[((size_t)bidb * 64 + q) * 2]     = M;
      if (h == 1) MLpart[((size_t)bidb * 64 + q) * 2 + 1] = L;
    }
  }
}

// ---------------------------------------------------------------------------
// attn_merge: combine the 1-4 slice partials of each (b, jt); write fp32 out.
// ---------------------------------------------------------------------------
__global__ __launch_bounds__(256) void attn_merge(
    const float* __restrict__ Opart, const float* __restrict__ MLpart,
    float* __restrict__ out)
{
  const int bid = blockIdx.x;
  const int bb = bid >> 6, jt = bid & 63;
  const int nsl = 1 + (jt >= 16) + (jt >= 32) + (jt >= 48);
  const int off = (jt < 16) ? jt
                : (jt < 32) ? 16 + 2 * (jt - 16)
                : (jt < 48) ? 48 + 3 * (jt - 32)
                :             96 + 4 * (jt - 48);
  const int pid0 = bb * 160 + off;
  const int t = threadIdx.x;
  const int q = t >> 2;
  const int hg = t & 3;
  const float CE = 0.36067376022224085f;

  float M = MLpart[((size_t)pid0 * 64 + q) * 2];
  for (int s2 = 1; s2 < nsl; ++s2)
    M = fmaxf(M, MLpart[((size_t)(pid0 + s2) * 64 + q) * 2]);

  float L = 0.f;
  float a[16];
#pragma unroll
  for (int j = 0; j < 16; ++j) a[j] = 0.f;

  for (int s2 = 0; s2 < nsl; ++s2) {
    size_t mlb = ((size_t)(pid0 + s2) * 64 + q) * 2;
    float w = __builtin_amdgcn_exp2f((MLpart[mlb] - M) * CE);
    L += w * MLpart[mlb + 1];
    const float* op = Opart + ((size_t)(pid0 + s2) * 64 + q) * 64 + hg * 16;
#pragma unroll
    for (int j = 0; j < 4; ++j) {
      float4 v4 = *reinterpret_cast<const float4*>(op + j * 4);
      a[j * 4 + 0] += w * v4.x; a[j * 4 + 1] += w * v4.y;
      a[j * 4 + 2] += w * v4.z; a[j * 4 + 3] += w * v4.w;
    }
  }

  const float inv = 1.f / L;
  float* po = out + ((size_t)bb * 4096 + jt * 64 + q) * 64 + hg * 16;
#pragma unroll
  for (int j = 0; j < 4; ++j) {
    float4 v4 = { a[j * 4] * inv, a[j * 4 + 1] * inv,
                  a[j * 4 + 2] * inv, a[j * 4 + 3] * inv };
    *reinterpret_cast<float4*>(po + j * 4) = v4;
  }
}

// ---------------------------------------------------------------------------
extern "C" void kernel_launch(void* const* d_in, const int* in_sizes, int n_in,
                              void* d_out, int out_size, void* d_ws, size_t ws_size,
                              hipStream_t stream) {
  const float* x  = (const float*)d_in[0];
  const float* Wq = (const float*)d_in[1];
  const float* Wk = (const float*)d_in[2];
  const float* Wv = (const float*)d_in[3];
  float* out = (float*)d_out;

  const size_t NE = (size_t)16384 * 64;
  unsigned short* qh  = (unsigned short*)d_ws;
  unsigned short* ql  = qh + NE;
  unsigned short* kh  = ql + NE;
  unsigned short* kl  = kh + NE;
  unsigned short* vth = kl + NE;
  unsigned short* vtl = vth + NE;
  unsigned short* wth = vtl + NE;
  unsigned short* wtl = wth + (size_t)192 * 1024;
  float* Opart  = (float*)(wtl + (size_t)192 * 1024);
  float* MLpart = Opart + (size_t)640 * 64 * 64;

  wprep<<<128, 192, 0, stream>>>(Wq, Wk, Wv, wth, wtl);
  qkv_proj<<<512, 256, 0, stream>>>(x, wth, wtl, qh, ql, kh, kl, vth, vtl);
  attn<<<640, 256, 0, stream>>>(qh, ql, kh, kl, vth, vtl, Opart, MLpart);
  attn_merge<<<256, 256, 0, stream>>>(Opart, MLpart, out);
}